// Round 1
// baseline (168.004 us; speedup 1.0000x reference)
//
#include <hip/hip_runtime.h>

// Problem constants (fixed by reference)
constexpr int BSZ = 4, SEQ = 2048, D = 128, H = 4, C = 128, E = 65536;
constexpr int N  = BSZ * SEQ;   // 8192 nodes
constexpr int HC = H * C;       // 512
constexpr int MAXE = 256;       // max (in-degree + 1) per node; Binom(65536,1/2048) max ~65

// ---------------- prep: w_src[h,d] = sum_c att_src[h,c] * W[h*C+c, d] ----------------
__global__ __launch_bounds__(256) void prep_w(const float* __restrict__ W,
                                              const float* __restrict__ att_src,
                                              const float* __restrict__ att_dst,
                                              float* __restrict__ w_src,
                                              float* __restrict__ w_dst) {
    int t = blockIdx.x * 256 + threadIdx.x;   // 512 total
    if (t >= H * D) return;
    int h = t >> 7, d = t & 127;
    float ws = 0.f, wd = 0.f;
    for (int c = 0; c < C; ++c) {
        float wv = W[(h * C + c) * D + d];
        ws += att_src[h * C + c] * wv;
        wd += att_dst[h * C + c] * wv;
    }
    w_src[t] = ws;
    w_dst[t] = wd;
}

// ---------------- a_src[n,h] = s[n,:] . w_src[h,:], same for dst ----------------
__global__ __launch_bounds__(256) void att_terms(const float* __restrict__ s,
                                                 const float* __restrict__ w_src,
                                                 const float* __restrict__ w_dst,
                                                 float* __restrict__ a_src,
                                                 float* __restrict__ a_dst) {
    int wave = threadIdx.x >> 6, lane = threadIdx.x & 63;
    int n = blockIdx.x * 4 + wave;
    float s0 = s[n * D + lane];
    float s1 = s[n * D + 64 + lane];
    #pragma unroll
    for (int h = 0; h < H; ++h) {
        float ps = s0 * w_src[h * D + lane] + s1 * w_src[h * D + 64 + lane];
        float pd = s0 * w_dst[h * D + lane] + s1 * w_dst[h * D + 64 + lane];
        #pragma unroll
        for (int off = 32; off; off >>= 1) {
            ps += __shfl_xor(ps, off);
            pd += __shfl_xor(pd, off);
        }
        if (lane == 0) {
            a_src[n * H + h] = ps;
            a_dst[n * H + h] = pd;
        }
    }
}

// ---------------- generic fp32 GEMM: Co[M,Nn] = A[M,K] @ B[Nn,K]^T (+bias) ----------------
template <int BM, int BN, int BK, bool BIAS>
__global__ __launch_bounds__(256) void gemm_bt(const float* __restrict__ A,
                                               const float* __restrict__ B,
                                               const float* __restrict__ bias,
                                               float* __restrict__ Co,
                                               int M, int Nn, int K) {
    __shared__ float As[BK][BM + 4];
    __shared__ float Bs[BK][BN + 4];
    const int tid = threadIdx.x;
    const int bx = blockIdx.x, by = blockIdx.y;
    const int tcols = BN / 4;                // 16
    const int tr = tid / tcols, tc = tid % tcols;
    float acc[4][4] = {};
    for (int k0 = 0; k0 < K; k0 += BK) {
        for (int v = tid; v < BM * BK / 4; v += 256) {
            int r = v / (BK / 4);
            int c4 = (v % (BK / 4)) * 4;
            const float4 f = *reinterpret_cast<const float4*>(&A[(size_t)(by * BM + r) * K + k0 + c4]);
            As[c4 + 0][r] = f.x; As[c4 + 1][r] = f.y; As[c4 + 2][r] = f.z; As[c4 + 3][r] = f.w;
        }
        for (int v = tid; v < BN * BK / 4; v += 256) {
            int r = v / (BK / 4);
            int c4 = (v % (BK / 4)) * 4;
            const float4 f = *reinterpret_cast<const float4*>(&B[(size_t)(bx * BN + r) * K + k0 + c4]);
            Bs[c4 + 0][r] = f.x; Bs[c4 + 1][r] = f.y; Bs[c4 + 2][r] = f.z; Bs[c4 + 3][r] = f.w;
        }
        __syncthreads();
        #pragma unroll
        for (int kk = 0; kk < BK; ++kk) {
            float4 av = *reinterpret_cast<const float4*>(&As[kk][tr * 4]);
            float4 bv = *reinterpret_cast<const float4*>(&Bs[kk][tc * 4]);
            float a[4] = {av.x, av.y, av.z, av.w};
            float b[4] = {bv.x, bv.y, bv.z, bv.w};
            #pragma unroll
            for (int m = 0; m < 4; ++m)
                #pragma unroll
                for (int n = 0; n < 4; ++n) acc[m][n] += a[m] * b[n];
        }
        __syncthreads();
    }
    int rowbase = by * BM + tr * 4;
    int colbase = bx * BN + tc * 4;
    #pragma unroll
    for (int m = 0; m < 4; ++m) {
        float4 o;
        if constexpr (BIAS) {
            o.x = acc[m][0] + bias[colbase + 0];
            o.y = acc[m][1] + bias[colbase + 1];
            o.z = acc[m][2] + bias[colbase + 2];
            o.w = acc[m][3] + bias[colbase + 3];
        } else {
            o.x = acc[m][0]; o.y = acc[m][1]; o.z = acc[m][2]; o.w = acc[m][3];
        }
        *reinterpret_cast<float4*>(&Co[(size_t)(rowbase + m) * Nn + colbase]) = o;
    }
}

// ---------------- CSR build ----------------
__global__ __launch_bounds__(256) void count_deg(const int* __restrict__ ei,
                                                 int* __restrict__ deg) {
    int e = blockIdx.x * 256 + threadIdx.x;
    if (e >= E) return;
    int dst = ei[E + e];
    #pragma unroll
    for (int b = 0; b < BSZ; ++b) atomicAdd(&deg[b * SEQ + dst], 1);
}

__global__ __launch_bounds__(1024) void scan_deg(const int* __restrict__ deg,
                                                 int* __restrict__ offs) {
    __shared__ int sums[1024];
    int t = threadIdx.x;
    int base = t * 8;
    int local[8];
    int s = 0;
    #pragma unroll
    for (int i = 0; i < 8; ++i) { local[i] = s; s += deg[base + i]; }
    sums[t] = s;
    __syncthreads();
    for (int off = 1; off < 1024; off <<= 1) {
        int v = (t >= off) ? sums[t - off] : 0;
        __syncthreads();
        sums[t] += v;
        __syncthreads();
    }
    int prefix = (t == 0) ? 0 : sums[t - 1];
    #pragma unroll
    for (int i = 0; i < 8; ++i) offs[base + i] = prefix + local[i];
    if (t == 1023) offs[N] = prefix + s;
}

__global__ __launch_bounds__(256) void fill_csr(const int* __restrict__ ei,
                                                const int* __restrict__ offs,
                                                int* __restrict__ cursor,
                                                int* __restrict__ csr) {
    int idx = blockIdx.x * 256 + threadIdx.x;
    if (idx >= BSZ * E) return;
    int b = idx >> 16;       // E == 65536
    int e = idx & 65535;
    int srcg = b * SEQ + ei[e];
    int dstg = b * SEQ + ei[E + e];
    int slot = atomicAdd(&cursor[dstg], 1);
    csr[offs[dstg] + slot] = srcg;
}

// ---------------- per-dst-node softmax + weighted aggregation ----------------
__global__ __launch_bounds__(256) void node_aggregate(const int* __restrict__ offs,
                                                      const int* __restrict__ csr,
                                                      const float* __restrict__ a_src,
                                                      const float* __restrict__ a_dst,
                                                      const float* __restrict__ x,
                                                      const float* __restrict__ bias,
                                                      float* __restrict__ agg) {
    __shared__ float sh_alpha[4][MAXE][H];
    __shared__ int   sh_src[4][MAXE];
    const int wave = threadIdx.x >> 6, lane = threadIdx.x & 63;
    const int n = blockIdx.x * 4 + wave;
    const int beg = offs[n];
    const int cnt = offs[n + 1] - beg + 1;   // + self loop
    float ad[H];
    #pragma unroll
    for (int h = 0; h < H; ++h) ad[h] = a_dst[n * H + h];
    float mx[H];
    #pragma unroll
    for (int h = 0; h < H; ++h) mx[h] = -1e30f;
    for (int i = lane; i < cnt; i += 64) {
        int sg = (i < cnt - 1) ? csr[beg + i] : n;
        sh_src[wave][i] = sg;
        #pragma unroll
        for (int h = 0; h < H; ++h) {
            float l = a_src[sg * H + h] + ad[h];
            l = (l > 0.f) ? l : 0.2f * l;
            sh_alpha[wave][i][h] = l;
            mx[h] = fmaxf(mx[h], l);
        }
    }
    #pragma unroll
    for (int h = 0; h < H; ++h)
        #pragma unroll
        for (int off = 32; off; off >>= 1) mx[h] = fmaxf(mx[h], __shfl_xor(mx[h], off));
    float sm[H] = {};
    for (int i = lane; i < cnt; i += 64) {
        #pragma unroll
        for (int h = 0; h < H; ++h) {
            float ev = expf(sh_alpha[wave][i][h] - mx[h]);
            sh_alpha[wave][i][h] = ev;
            sm[h] += ev;
        }
    }
    #pragma unroll
    for (int h = 0; h < H; ++h)
        #pragma unroll
        for (int off = 32; off; off >>= 1) sm[h] += __shfl_xor(sm[h], off);
    __syncthreads();   // sh_alpha/sh_src now visible to all lanes of the wave
    float inv[H];
    #pragma unroll
    for (int h = 0; h < H; ++h) inv[h] = 1.f / sm[h];
    float acc[8] = {};
    for (int i = 0; i < cnt; ++i) {
        const int sg = sh_src[wave][i];
        const float* xr = x + (size_t)sg * HC;
        #pragma unroll
        for (int j = 0; j < 8; ++j) {
            float al = sh_alpha[wave][i][j >> 1];     // head = (lane+64j)>>7 = j>>1
            acc[j] += al * xr[lane + 64 * j];
        }
    }
    #pragma unroll
    for (int j = 0; j < 8; ++j) {
        int col = lane + 64 * j;
        agg[(size_t)n * HC + col] = acc[j] * inv[j >> 1] + bias[col];
    }
}

extern "C" void kernel_launch(void* const* d_in, const int* in_sizes, int n_in,
                              void* d_out, int out_size, void* d_ws, size_t ws_size,
                              hipStream_t stream) {
    const float* s       = (const float*)d_in[0];
    const int*   ei      = (const int*)d_in[1];
    const float* W       = (const float*)d_in[2];
    const float* att_src = (const float*)d_in[3];
    const float* att_dst = (const float*)d_in[4];
    const float* bias    = (const float*)d_in[5];
    const float* Wo      = (const float*)d_in[6];
    const float* bo      = (const float*)d_in[7];
    float* out = (float*)d_out;

    char* ws = (char*)d_ws;
    float* w_src = (float*)ws; ws += 512 * 4;
    float* w_dst = (float*)ws; ws += 512 * 4;
    float* a_src = (float*)ws; ws += (size_t)N * H * 4;
    float* a_dst = (float*)ws; ws += (size_t)N * H * 4;
    float* x     = (float*)ws; ws += (size_t)N * HC * 4;
    float* agg   = (float*)ws; ws += (size_t)N * HC * 4;
    int* deg     = (int*)ws;   ws += (size_t)N * 4;
    int* cursor  = (int*)ws;   ws += (size_t)N * 4;
    int* offs    = (int*)ws;   ws += (size_t)(N + 1) * 4;
    int* csr     = (int*)ws;   ws += (size_t)BSZ * E * 4;

    hipMemsetAsync(deg, 0, 2 * N * 4, stream);   // deg + cursor (adjacent)

    prep_w<<<2, 256, 0, stream>>>(W, att_src, att_dst, w_src, w_dst);
    gemm_bt<64, 64, 32, false><<<dim3(HC / 64, N / 64), 256, 0, stream>>>(s, W, nullptr, x, N, HC, D);
    att_terms<<<N / 4, 256, 0, stream>>>(s, w_src, w_dst, a_src, a_dst);
    count_deg<<<E / 256, 256, 0, stream>>>(ei, deg);
    scan_deg<<<1, 1024, 0, stream>>>(deg, offs);
    fill_csr<<<BSZ * E / 256, 256, 0, stream>>>(ei, offs, cursor, csr);
    node_aggregate<<<N / 4, 256, 0, stream>>>(offs, csr, a_src, a_dst, x, bias, agg);
    gemm_bt<64, 64, 32, true><<<dim3(D / 64, N / 64), 256, 0, stream>>>(agg, Wo, bo, out, N, D, HC);
}

// Round 2
// 98.156 us; speedup vs baseline: 1.7116x; 1.7116x over previous
//
#include <hip/hip_runtime.h>

// Problem constants (fixed by reference)
constexpr int BSZ = 4, SEQ = 2048, D = 128, H = 4, E = 65536;
constexpr int N  = BSZ * SEQ;   // 8192 nodes
constexpr int HC = H * D;       // 512
constexpr int MAXE = 160;       // max (in-degree + 1); Binom(65536,1/2048): mean 32, max ~66

typedef __attribute__((ext_vector_type(8))) short s16x8;
typedef __attribute__((ext_vector_type(4))) float f32x4;

__device__ inline unsigned short f2bf(float v) {            // fp32 -> bf16 RNE
    unsigned u = __float_as_uint(v);
    return (unsigned short)((u + 0x7fffu + ((u >> 16) & 1u)) >> 16);
}
__device__ inline float bf2f(unsigned short h) { return __uint_as_float(((unsigned)h) << 16); }

// ---------------- prep: w_src[h,d] = sum_c att_src[h,c] * W[h*C+c, d] ----------------
__global__ __launch_bounds__(256) void prep_w(const float* __restrict__ W,
                                              const float* __restrict__ att_src,
                                              const float* __restrict__ att_dst,
                                              float* __restrict__ w_src,
                                              float* __restrict__ w_dst) {
    int t = blockIdx.x * 256 + threadIdx.x;   // 512 total
    if (t >= H * D) return;
    int h = t >> 7, d = t & 127;
    float ws = 0.f, wd = 0.f;
    for (int c = 0; c < D; ++c) {
        float wv = W[(h * D + c) * D + d];
        ws += att_src[h * D + c] * wv;
        wd += att_dst[h * D + c] * wv;
    }
    w_src[t] = ws;
    w_dst[t] = wd;
}

// ---------------- a_src[n,h] = s[n,:] . w_src[h,:], same for dst ----------------
__global__ __launch_bounds__(256) void att_terms(const float* __restrict__ s,
                                                 const float* __restrict__ w_src,
                                                 const float* __restrict__ w_dst,
                                                 float* __restrict__ a_src,
                                                 float* __restrict__ a_dst) {
    int wave = threadIdx.x >> 6, lane = threadIdx.x & 63;
    int n = blockIdx.x * 4 + wave;
    float s0 = s[n * D + lane];
    float s1 = s[n * D + 64 + lane];
    #pragma unroll
    for (int h = 0; h < H; ++h) {
        float ps = s0 * w_src[h * D + lane] + s1 * w_src[h * D + 64 + lane];
        float pd = s0 * w_dst[h * D + lane] + s1 * w_dst[h * D + 64 + lane];
        #pragma unroll
        for (int off = 32; off; off >>= 1) {
            ps += __shfl_xor(ps, off);
            pd += __shfl_xor(pd, off);
        }
        if (lane == 0) {
            a_src[n * H + h] = ps;
            a_dst[n * H + h] = pd;
        }
    }
}

// ---------------- Pcat[d, h*128+k] = sum_c Wo[d, h*128+c] * W[h*128+c, k], split bf16 ----
__global__ __launch_bounds__(256) void prep_P(const float* __restrict__ W,
                                              const float* __restrict__ Wo,
                                              unsigned short* __restrict__ p_hi,
                                              unsigned short* __restrict__ p_lo) {
    int h = blockIdx.x;                       // 4
    int d = blockIdx.y * 2 + (threadIdx.x >> 7);
    int k = threadIdx.x & 127;
    float acc = 0.f;
    for (int c = 0; c < D; ++c)
        acc += Wo[d * HC + h * D + c] * W[(h * D + c) * D + k];
    unsigned short hi = f2bf(acc);
    unsigned short lo = f2bf(acc - bf2f(hi));
    p_hi[d * HC + h * D + k] = hi;
    p_lo[d * HC + h * D + k] = lo;
}

// ---------------- cvec[d] = sum_j bias[j]*Wo[d,j] + bo[d] ----------------
__global__ __launch_bounds__(256) void prep_c(const float* __restrict__ bias,
                                              const float* __restrict__ Wo,
                                              const float* __restrict__ bo,
                                              float* __restrict__ cvec) {
    __shared__ float part[4];
    int d = blockIdx.x, t = threadIdx.x;
    float a = bias[t] * Wo[d * HC + t] + bias[t + 256] * Wo[d * HC + t + 256];
    #pragma unroll
    for (int off = 32; off; off >>= 1) a += __shfl_xor(a, off);
    if ((t & 63) == 0) part[t >> 6] = a;
    __syncthreads();
    if (t == 0) cvec[d] = part[0] + part[1] + part[2] + part[3] + bo[d];
}

// ---------------- CSR build over the SHARED per-batch edge list (2048 local nodes) ----
__global__ __launch_bounds__(256) void count_deg(const int* __restrict__ ei,
                                                 int* __restrict__ deg) {
    int e = blockIdx.x * 256 + threadIdx.x;
    atomicAdd(&deg[ei[E + e]], 1);
}

__global__ __launch_bounds__(256) void scan_deg(const int* __restrict__ deg,
                                                int* __restrict__ offs) {
    __shared__ int sums[256];
    int t = threadIdx.x;
    int local[8];
    int s = 0;
    #pragma unroll
    for (int i = 0; i < 8; ++i) { local[i] = s; s += deg[t * 8 + i]; }
    sums[t] = s;
    __syncthreads();
    for (int off = 1; off < 256; off <<= 1) {
        int v = (t >= off) ? sums[t - off] : 0;
        __syncthreads();
        sums[t] += v;
        __syncthreads();
    }
    int prefix = (t > 0) ? sums[t - 1] : 0;
    #pragma unroll
    for (int i = 0; i < 8; ++i) offs[t * 8 + i] = prefix + local[i];
    if (t == 255) offs[SEQ] = prefix + s;
}

__global__ __launch_bounds__(256) void fill_csr(const int* __restrict__ ei,
                                                const int* __restrict__ offs,
                                                int* __restrict__ cursor,
                                                int* __restrict__ csr0) {
    int e = blockIdx.x * 256 + threadIdx.x;
    int dst = ei[E + e];
    int slot = atomicAdd(&cursor[dst], 1);
    csr0[offs[dst] + slot] = ei[e];   // local src id
}

// ---------------- per-dst softmax + gather of s rows -> z (split bf16) ----------------
__global__ __launch_bounds__(256) void node_aggregate_z(const int* __restrict__ offs0,
                                                        const int* __restrict__ csr0,
                                                        const float* __restrict__ a_src,
                                                        const float* __restrict__ a_dst,
                                                        const float* __restrict__ s,
                                                        unsigned short* __restrict__ z_hi,
                                                        unsigned short* __restrict__ z_lo) {
    __shared__ float sh_alpha[4][MAXE][H];
    __shared__ int   sh_src[4][MAXE];
    const int wave = threadIdx.x >> 6, lane = threadIdx.x & 63;
    const int n = blockIdx.x * 4 + wave;
    const int b = n >> 11, dloc = n & 2047;
    const int beg = offs0[dloc];
    const int deg = offs0[dloc + 1] - beg;
    const int cnt = deg + 1;                      // + self loop
    float4 adv = *reinterpret_cast<const float4*>(&a_dst[n * H]);
    float ad[4] = {adv.x, adv.y, adv.z, adv.w};
    float mx[4] = {-1e30f, -1e30f, -1e30f, -1e30f};
    for (int i = lane; i < cnt; i += 64) {
        int sg = (i < deg) ? (csr0[beg + i] + (b << 11)) : n;
        sh_src[wave][i] = sg;
        float4 asv = *reinterpret_cast<const float4*>(&a_src[sg * H]);
        float lg[4] = {asv.x, asv.y, asv.z, asv.w};
        #pragma unroll
        for (int h = 0; h < 4; ++h) {
            float l = lg[h] + ad[h];
            l = (l > 0.f) ? l : 0.2f * l;
            sh_alpha[wave][i][h] = l;
            mx[h] = fmaxf(mx[h], l);
        }
    }
    #pragma unroll
    for (int h = 0; h < 4; ++h)
        #pragma unroll
        for (int off = 32; off; off >>= 1) mx[h] = fmaxf(mx[h], __shfl_xor(mx[h], off));
    float sm[4] = {0.f, 0.f, 0.f, 0.f};
    for (int i = lane; i < cnt; i += 64) {
        #pragma unroll
        for (int h = 0; h < 4; ++h) {
            float ev = expf(sh_alpha[wave][i][h] - mx[h]);
            sh_alpha[wave][i][h] = ev;
            sm[h] += ev;
        }
    }
    #pragma unroll
    for (int h = 0; h < 4; ++h)
        #pragma unroll
        for (int off = 32; off; off >>= 1) sm[h] += __shfl_xor(sm[h], off);
    __syncthreads();
    float inv[4];
    #pragma unroll
    for (int h = 0; h < 4; ++h) inv[h] = 1.f / sm[h];

    const int coff = lane * 2;
    float ax[4] = {0.f, 0.f, 0.f, 0.f}, ay[4] = {0.f, 0.f, 0.f, 0.f};
    int i = 0;
    for (; i + 2 <= cnt; i += 2) {
        int sg0 = sh_src[wave][i], sg1 = sh_src[wave][i + 1];
        float2 sv0 = *reinterpret_cast<const float2*>(&s[(size_t)sg0 * D + coff]);
        float2 sv1 = *reinterpret_cast<const float2*>(&s[(size_t)sg1 * D + coff]);
        float4 al0 = *reinterpret_cast<const float4*>(&sh_alpha[wave][i][0]);
        float4 al1 = *reinterpret_cast<const float4*>(&sh_alpha[wave][i + 1][0]);
        float a0[4] = {al0.x, al0.y, al0.z, al0.w};
        float a1[4] = {al1.x, al1.y, al1.z, al1.w};
        #pragma unroll
        for (int h = 0; h < 4; ++h) {
            ax[h] += a0[h] * sv0.x + a1[h] * sv1.x;
            ay[h] += a0[h] * sv0.y + a1[h] * sv1.y;
        }
    }
    if (i < cnt) {
        int sg0 = sh_src[wave][i];
        float2 sv0 = *reinterpret_cast<const float2*>(&s[(size_t)sg0 * D + coff]);
        float4 al0 = *reinterpret_cast<const float4*>(&sh_alpha[wave][i][0]);
        float a0[4] = {al0.x, al0.y, al0.z, al0.w};
        #pragma unroll
        for (int h = 0; h < 4; ++h) {
            ax[h] += a0[h] * sv0.x;
            ay[h] += a0[h] * sv0.y;
        }
    }
    #pragma unroll
    for (int h = 0; h < 4; ++h) {
        float vx = ax[h] * inv[h], vy = ay[h] * inv[h];
        unsigned short hx = f2bf(vx), hy = f2bf(vy);
        ushort2 zh, zl;
        zh.x = hx; zh.y = hy;
        zl.x = f2bf(vx - bf2f(hx)); zl.y = f2bf(vy - bf2f(hy));
        *reinterpret_cast<ushort2*>(&z_hi[(size_t)n * HC + h * D + coff]) = zh;
        *reinterpret_cast<ushort2*>(&z_lo[(size_t)n * HC + h * D + coff]) = zl;
    }
}

// ---------------- out[m,d] = z[m,:] . Pcat[d,:] + cvec[d]  (split-bf16 MFMA) ----------
__global__ __launch_bounds__(256) void out_mfma(const unsigned short* __restrict__ z_hi,
                                                const unsigned short* __restrict__ z_lo,
                                                const unsigned short* __restrict__ p_hi,
                                                const unsigned short* __restrict__ p_lo,
                                                const float* __restrict__ cvec,
                                                float* __restrict__ out) {
    const int wave = threadIdx.x >> 6, lane = threadIdx.x & 63;
    const int n0 = blockIdx.x * 32;                 // d-col block (4 blocks)
    const int m0 = blockIdx.y * 64 + wave * 16;     // node-row block
    const int lrow = lane & 15, lk8 = (lane >> 4) * 8;
    f32x4 acc0 = {0.f, 0.f, 0.f, 0.f}, acc1 = {0.f, 0.f, 0.f, 0.f};
    const unsigned short* za = z_hi + (size_t)(m0 + lrow) * HC + lk8;
    const unsigned short* zb = z_lo + (size_t)(m0 + lrow) * HC + lk8;
    const unsigned short* ph0 = p_hi + (size_t)(n0 + lrow) * HC + lk8;
    const unsigned short* pl0 = p_lo + (size_t)(n0 + lrow) * HC + lk8;
    const unsigned short* ph1 = p_hi + (size_t)(n0 + 16 + lrow) * HC + lk8;
    const unsigned short* pl1 = p_lo + (size_t)(n0 + 16 + lrow) * HC + lk8;
    #pragma unroll 2
    for (int ks = 0; ks < HC; ks += 32) {
        s16x8 ah  = *reinterpret_cast<const s16x8*>(za + ks);
        s16x8 al  = *reinterpret_cast<const s16x8*>(zb + ks);
        s16x8 bh0 = *reinterpret_cast<const s16x8*>(ph0 + ks);
        s16x8 bl0 = *reinterpret_cast<const s16x8*>(pl0 + ks);
        s16x8 bh1 = *reinterpret_cast<const s16x8*>(ph1 + ks);
        s16x8 bl1 = *reinterpret_cast<const s16x8*>(pl1 + ks);
        acc0 = __builtin_amdgcn_mfma_f32_16x16x32_bf16(ah, bh0, acc0, 0, 0, 0);
        acc0 = __builtin_amdgcn_mfma_f32_16x16x32_bf16(ah, bl0, acc0, 0, 0, 0);
        acc0 = __builtin_amdgcn_mfma_f32_16x16x32_bf16(al, bh0, acc0, 0, 0, 0);
        acc1 = __builtin_amdgcn_mfma_f32_16x16x32_bf16(ah, bh1, acc1, 0, 0, 0);
        acc1 = __builtin_amdgcn_mfma_f32_16x16x32_bf16(ah, bl1, acc1, 0, 0, 0);
        acc1 = __builtin_amdgcn_mfma_f32_16x16x32_bf16(al, bh1, acc1, 0, 0, 0);
    }
    // C/D layout (m89-verified): col = lane&15, row = (lane>>4)*4 + reg
    const int ocol = n0 + (lane & 15);
    const int orow = m0 + (lane >> 4) * 4;
    const float c0 = cvec[ocol], c1 = cvec[ocol + 16];
    #pragma unroll
    for (int r = 0; r < 4; ++r) {
        out[(size_t)(orow + r) * D + ocol]      = acc0[r] + c0;
        out[(size_t)(orow + r) * D + ocol + 16] = acc1[r] + c1;
    }
}

extern "C" void kernel_launch(void* const* d_in, const int* in_sizes, int n_in,
                              void* d_out, int out_size, void* d_ws, size_t ws_size,
                              hipStream_t stream) {
    const float* s       = (const float*)d_in[0];
    const int*   ei      = (const int*)d_in[1];
    const float* W       = (const float*)d_in[2];
    const float* att_src = (const float*)d_in[3];
    const float* att_dst = (const float*)d_in[4];
    const float* bias    = (const float*)d_in[5];
    const float* Wo      = (const float*)d_in[6];
    const float* bo      = (const float*)d_in[7];
    float* out = (float*)d_out;

    char* ws = (char*)d_ws;
    float* w_src = (float*)ws; ws += 512 * 4;
    float* w_dst = (float*)ws; ws += 512 * 4;
    float* a_src = (float*)ws; ws += (size_t)N * H * 4;
    float* a_dst = (float*)ws; ws += (size_t)N * H * 4;
    float* cvec  = (float*)ws; ws += 512;                      // 128 floats + pad
    unsigned short* z_hi = (unsigned short*)ws; ws += (size_t)N * HC * 2;
    unsigned short* z_lo = (unsigned short*)ws; ws += (size_t)N * HC * 2;
    unsigned short* p_hi = (unsigned short*)ws; ws += (size_t)D * HC * 2;
    unsigned short* p_lo = (unsigned short*)ws; ws += (size_t)D * HC * 2;
    int* deg    = (int*)ws; ws += SEQ * 4;
    int* cursor = (int*)ws; ws += SEQ * 4;
    int* offs0  = (int*)ws; ws += (SEQ + 1) * 4;
    int* csr0   = (int*)ws; ws += (size_t)E * 4;

    hipMemsetAsync(deg, 0, 2 * SEQ * 4, stream);   // deg + cursor (adjacent)

    prep_w<<<2, 256, 0, stream>>>(W, att_src, att_dst, w_src, w_dst);
    att_terms<<<N / 4, 256, 0, stream>>>(s, w_src, w_dst, a_src, a_dst);
    count_deg<<<E / 256, 256, 0, stream>>>(ei, deg);
    scan_deg<<<1, 256, 0, stream>>>(deg, offs0);
    fill_csr<<<E / 256, 256, 0, stream>>>(ei, offs0, cursor, csr0);
    prep_P<<<dim3(4, 64), 256, 0, stream>>>(W, Wo, p_hi, p_lo);
    prep_c<<<128, 256, 0, stream>>>(bias, Wo, bo, cvec);
    node_aggregate_z<<<N / 4, 256, 0, stream>>>(offs0, csr0, a_src, a_dst, s, z_hi, z_lo);
    out_mfma<<<dim3(4, 128), 256, 0, stream>>>(z_hi, z_lo, p_hi, p_lo, cvec, out);
}

// Round 3
// 96.880 us; speedup vs baseline: 1.7341x; 1.0132x over previous
//
#include <hip/hip_runtime.h>

// Problem constants (fixed by reference)
constexpr int BSZ = 4, SEQ = 2048, D = 128, H = 4, E = 65536;
constexpr int N  = BSZ * SEQ;   // 8192 nodes
constexpr int HC = H * D;       // 512
constexpr int SLOTS = 128;      // per-dst bucket capacity; in-deg ~ Binom(65536,1/2048), mean 32
constexpr int MAXE  = SLOTS + 4;

typedef __attribute__((ext_vector_type(8))) short s16x8;
typedef __attribute__((ext_vector_type(4))) float f32x4;

__device__ inline unsigned short f2bf(float v) {            // fp32 -> bf16 RNE
    unsigned u = __float_as_uint(v);
    return (unsigned short)((u + 0x7fffu + ((u >> 16) & 1u)) >> 16);
}
__device__ inline float bf2f(unsigned short h) { return __uint_as_float(((unsigned)h) << 16); }

// ================= prep_all: block-specialized =================
// b in [0,256)   : Pcat[d, h*128+k] = sum_c Wo[d,h*128+c] * W[h*128+c, k]  (split bf16)
// b in [256,384) : cvec[d] = sum_j bias[j]*Wo[d,j] + bo[d]
// b in [384,386) : w_src[h,d] = sum_c att_src[h,c]*W[h*128+c, d]  (and w_dst)
// b in [386,394) : zero cursor[0..2047]
__global__ __launch_bounds__(256) void prep_all(const float* __restrict__ W,
                                                const float* __restrict__ att_src,
                                                const float* __restrict__ att_dst,
                                                const float* __restrict__ bias,
                                                const float* __restrict__ Wo,
                                                const float* __restrict__ bo,
                                                float* __restrict__ w_src,
                                                float* __restrict__ w_dst,
                                                unsigned short* __restrict__ p_hi,
                                                unsigned short* __restrict__ p_lo,
                                                float* __restrict__ cvec,
                                                int* __restrict__ cursor) {
    __shared__ float part[4];
    const int b = blockIdx.x, tid = threadIdx.x;
    if (b < 256) {                      // --- prep_P ---
        int h = b & 3;
        int d = (b >> 2) * 2 + (tid >> 7);
        int k = tid & 127;
        float acc = 0.f;
        for (int c = 0; c < D; ++c)
            acc += Wo[d * HC + h * D + c] * W[(h * D + c) * D + k];
        unsigned short hi = f2bf(acc);
        p_hi[d * HC + h * D + k] = hi;
        p_lo[d * HC + h * D + k] = f2bf(acc - bf2f(hi));
    } else if (b < 384) {               // --- prep_c ---
        int d = b - 256;
        float a = bias[tid] * Wo[d * HC + tid] + bias[tid + 256] * Wo[d * HC + tid + 256];
        #pragma unroll
        for (int off = 32; off; off >>= 1) a += __shfl_xor(a, off);
        if ((tid & 63) == 0) part[tid >> 6] = a;
        __syncthreads();
        if (tid == 0) cvec[d] = part[0] + part[1] + part[2] + part[3] + bo[d];
    } else if (b < 386) {               // --- prep_w ---
        int t = (b - 384) * 256 + tid;  // 0..511
        int h = t >> 7, dd = t & 127;
        float ws = 0.f, wd = 0.f;
        for (int c = 0; c < D; ++c) {
            float wv = W[(h * D + c) * D + dd];
            ws += att_src[h * D + c] * wv;
            wd += att_dst[h * D + c] * wv;
        }
        w_src[t] = ws;
        w_dst[t] = wd;
    } else {                            // --- zero cursor ---
        int idx = (b - 386) * 256 + tid;
        if (idx < SEQ) cursor[idx] = 0;
    }
}

// ======== att_fill: a_src/a_dst per node; first 256 blocks also bucket the edges ========
__global__ __launch_bounds__(256) void att_fill(const float* __restrict__ s,
                                                const float* __restrict__ w_src,
                                                const float* __restrict__ w_dst,
                                                const int* __restrict__ ei,
                                                float* __restrict__ a_src,
                                                float* __restrict__ a_dst,
                                                int* __restrict__ cursor,
                                                int* __restrict__ csr0) {
    const int bid = blockIdx.x, tid = threadIdx.x;
    if (bid < 256) {                    // bucket-fill: one edge per thread
        int e = bid * 256 + tid;
        int src = ei[e], dst = ei[E + e];
        int slot = atomicAdd(&cursor[dst], 1);
        if (slot < SLOTS) csr0[dst * SLOTS + slot] = src;
    }
    const int wave = tid >> 6, lane = tid & 63;
    const int n = bid * 4 + wave;
    float s0 = s[n * D + lane];
    float s1 = s[n * D + 64 + lane];
    #pragma unroll
    for (int h = 0; h < H; ++h) {
        float ps = s0 * w_src[h * D + lane] + s1 * w_src[h * D + 64 + lane];
        float pd = s0 * w_dst[h * D + lane] + s1 * w_dst[h * D + 64 + lane];
        #pragma unroll
        for (int off = 32; off; off >>= 1) {
            ps += __shfl_xor(ps, off);
            pd += __shfl_xor(pd, off);
        }
        if (lane == 0) {
            a_src[n * H + h] = ps;
            a_dst[n * H + h] = pd;
        }
    }
}

// ======== per-dst softmax + gather of s rows -> z (split bf16) ========
__global__ __launch_bounds__(256) void node_aggregate_z(const int* __restrict__ cursor,
                                                        const int* __restrict__ csr0,
                                                        const float* __restrict__ a_src,
                                                        const float* __restrict__ a_dst,
                                                        const float* __restrict__ s,
                                                        unsigned short* __restrict__ z_hi,
                                                        unsigned short* __restrict__ z_lo) {
    __shared__ float sh_alpha[4][MAXE][4];
    __shared__ int   sh_src[4][MAXE];
    const int wave = threadIdx.x >> 6, lane = threadIdx.x & 63;
    const int n = blockIdx.x * 4 + wave;
    const int b = n >> 11, dloc = n & 2047;
    int deg = cursor[dloc];
    deg = (deg < SLOTS) ? deg : SLOTS;
    const int beg = dloc * SLOTS;
    const int cnt = deg + 1;                      // + self loop
    float4 adv = *reinterpret_cast<const float4*>(&a_dst[n * H]);
    float ad[4] = {adv.x, adv.y, adv.z, adv.w};
    float mx[4] = {-1e30f, -1e30f, -1e30f, -1e30f};
    for (int i = lane; i < cnt; i += 64) {
        int sg = (i < deg) ? (csr0[beg + i] + (b << 11)) : n;
        sh_src[wave][i] = sg;
        float4 asv = *reinterpret_cast<const float4*>(&a_src[sg * H]);
        float lg[4] = {asv.x, asv.y, asv.z, asv.w};
        #pragma unroll
        for (int h = 0; h < 4; ++h) {
            float l = lg[h] + ad[h];
            l = (l > 0.f) ? l : 0.2f * l;
            sh_alpha[wave][i][h] = l;
            mx[h] = fmaxf(mx[h], l);
        }
    }
    #pragma unroll
    for (int h = 0; h < 4; ++h)
        #pragma unroll
        for (int off = 32; off; off >>= 1) mx[h] = fmaxf(mx[h], __shfl_xor(mx[h], off));
    float sm[4] = {0.f, 0.f, 0.f, 0.f};
    for (int i = lane; i < cnt; i += 64) {
        #pragma unroll
        for (int h = 0; h < 4; ++h) {
            float ev = expf(sh_alpha[wave][i][h] - mx[h]);
            sh_alpha[wave][i][h] = ev;
            sm[h] += ev;
        }
    }
    #pragma unroll
    for (int h = 0; h < 4; ++h)
        #pragma unroll
        for (int off = 32; off; off >>= 1) sm[h] += __shfl_xor(sm[h], off);
    __syncthreads();
    float inv[4];
    #pragma unroll
    for (int h = 0; h < 4; ++h) inv[h] = 1.f / sm[h];

    // gather: lanes 0-31 take even edges, lanes 32-63 odd edges; float4 (4 cols) per lane
    const int half = lane >> 5, l32 = lane & 31;
    const int coff = l32 * 4;
    float acc[4][4] = {};                 // [head][col]
    for (int i = 0; i < cnt; i += 2) {
        int ii = i + half;
        if (ii < cnt) {
            int sg = sh_src[wave][ii];
            float4 sv = *reinterpret_cast<const float4*>(&s[(size_t)sg * D + coff]);
            float4 alv = *reinterpret_cast<const float4*>(&sh_alpha[wave][ii][0]);
            float al[4] = {alv.x, alv.y, alv.z, alv.w};
            float cv[4] = {sv.x, sv.y, sv.z, sv.w};
            #pragma unroll
            for (int h = 0; h < 4; ++h)
                #pragma unroll
                for (int c = 0; c < 4; ++c) acc[h][c] += al[h] * cv[c];
        }
    }
    #pragma unroll
    for (int h = 0; h < 4; ++h)
        #pragma unroll
        for (int c = 0; c < 4; ++c) acc[h][c] += __shfl_xor(acc[h][c], 32);
    // this lane writes heads {half*2, half*2+1}, cols coff..coff+3
    #pragma unroll
    for (int hh = 0; hh < 2; ++hh) {
        int h = half * 2 + hh;
        ushort4 zh, zl;
        float v0 = acc[h][0] * inv[h], v1 = acc[h][1] * inv[h];
        float v2 = acc[h][2] * inv[h], v3 = acc[h][3] * inv[h];
        zh.x = f2bf(v0); zh.y = f2bf(v1); zh.z = f2bf(v2); zh.w = f2bf(v3);
        zl.x = f2bf(v0 - bf2f(zh.x)); zl.y = f2bf(v1 - bf2f(zh.y));
        zl.z = f2bf(v2 - bf2f(zh.z)); zl.w = f2bf(v3 - bf2f(zh.w));
        *reinterpret_cast<ushort4*>(&z_hi[(size_t)n * HC + h * D + coff]) = zh;
        *reinterpret_cast<ushort4*>(&z_lo[(size_t)n * HC + h * D + coff]) = zl;
    }
}

// ======== out[m,d] = z[m,:] . Pcat[d,:] + cvec[d]  (split-bf16 MFMA, z read once) ========
__global__ __launch_bounds__(256) void out_mfma(const unsigned short* __restrict__ z_hi,
                                                const unsigned short* __restrict__ z_lo,
                                                const unsigned short* __restrict__ p_hi,
                                                const unsigned short* __restrict__ p_lo,
                                                const float* __restrict__ cvec,
                                                float* __restrict__ out) {
    const int wave = threadIdx.x >> 6, lane = threadIdx.x & 63;
    const int m0 = blockIdx.x * 64 + wave * 16;     // 16 node-rows per wave
    const int lrow = lane & 15, lk8 = (lane >> 4) * 8;
    f32x4 acc[8] = {};                              // 8 col-tiles of 16 = 128 cols
    const unsigned short* za = z_hi + (size_t)(m0 + lrow) * HC + lk8;
    const unsigned short* zb = z_lo + (size_t)(m0 + lrow) * HC + lk8;
    for (int ks = 0; ks < HC; ks += 32) {
        s16x8 ah = *reinterpret_cast<const s16x8*>(za + ks);
        s16x8 al = *reinterpret_cast<const s16x8*>(zb + ks);
        #pragma unroll
        for (int ct = 0; ct < 8; ++ct) {
            s16x8 bh = *reinterpret_cast<const s16x8*>(p_hi + (size_t)(ct * 16 + lrow) * HC + ks + lk8);
            s16x8 bl = *reinterpret_cast<const s16x8*>(p_lo + (size_t)(ct * 16 + lrow) * HC + ks + lk8);
            acc[ct] = __builtin_amdgcn_mfma_f32_16x16x32_bf16(ah, bh, acc[ct], 0, 0, 0);
            acc[ct] = __builtin_amdgcn_mfma_f32_16x16x32_bf16(ah, bl, acc[ct], 0, 0, 0);
            acc[ct] = __builtin_amdgcn_mfma_f32_16x16x32_bf16(al, bh, acc[ct], 0, 0, 0);
        }
    }
    // C/D layout: col = lane&15, row = (lane>>4)*4 + reg
    const int orow = m0 + (lane >> 4) * 4;
    #pragma unroll
    for (int ct = 0; ct < 8; ++ct) {
        const int ocol = ct * 16 + (lane & 15);
        const float cb = cvec[ocol];
        #pragma unroll
        for (int r = 0; r < 4; ++r)
            out[(size_t)(orow + r) * D + ocol] = acc[ct][r] + cb;
    }
}

extern "C" void kernel_launch(void* const* d_in, const int* in_sizes, int n_in,
                              void* d_out, int out_size, void* d_ws, size_t ws_size,
                              hipStream_t stream) {
    const float* s       = (const float*)d_in[0];
    const int*   ei      = (const int*)d_in[1];
    const float* W       = (const float*)d_in[2];
    const float* att_src = (const float*)d_in[3];
    const float* att_dst = (const float*)d_in[4];
    const float* bias    = (const float*)d_in[5];
    const float* Wo      = (const float*)d_in[6];
    const float* bo      = (const float*)d_in[7];
    float* out = (float*)d_out;

    char* ws = (char*)d_ws;
    float* w_src = (float*)ws; ws += 512 * 4;
    float* w_dst = (float*)ws; ws += 512 * 4;
    float* a_src = (float*)ws; ws += (size_t)N * H * 4;
    float* a_dst = (float*)ws; ws += (size_t)N * H * 4;
    float* cvec  = (float*)ws; ws += 512;
    unsigned short* z_hi = (unsigned short*)ws; ws += (size_t)N * HC * 2;
    unsigned short* z_lo = (unsigned short*)ws; ws += (size_t)N * HC * 2;
    unsigned short* p_hi = (unsigned short*)ws; ws += (size_t)D * HC * 2;
    unsigned short* p_lo = (unsigned short*)ws; ws += (size_t)D * HC * 2;
    int* cursor = (int*)ws; ws += SEQ * 4;
    int* csr0   = (int*)ws; ws += (size_t)SEQ * SLOTS * 4;

    prep_all<<<394, 256, 0, stream>>>(W, att_src, att_dst, bias, Wo, bo,
                                      w_src, w_dst, p_hi, p_lo, cvec, cursor);
    att_fill<<<N / 4, 256, 0, stream>>>(s, w_src, w_dst, ei, a_src, a_dst, cursor, csr0);
    node_aggregate_z<<<N / 4, 256, 0, stream>>>(cursor, csr0, a_src, a_dst, s, z_hi, z_lo);
    out_mfma<<<N / 64, 256, 0, stream>>>(z_hi, z_lo, p_hi, p_lo, cvec, out);
}

// Round 4
// 70.132 us; speedup vs baseline: 2.3955x; 1.3814x over previous
//
#include <hip/hip_runtime.h>

// Problem constants (fixed by reference)
constexpr int BSZ = 4, SEQ = 2048, D = 128, H = 4, E = 65536;
constexpr int N  = BSZ * SEQ;   // 8192 nodes
constexpr int HC = H * D;       // 512
constexpr int SLOTS = 128;      // per-dst bucket capacity; in-deg ~ Binom(65536,1/2048), mean 32
constexpr int MAXE  = SLOTS + 4;

typedef __attribute__((ext_vector_type(8))) short s16x8;
typedef __attribute__((ext_vector_type(4))) float f32x4;

__device__ inline unsigned short f2bf(float v) {            // fp32 -> bf16 RNE
    unsigned u = __float_as_uint(v);
    return (unsigned short)((u + 0x7fffu + ((u >> 16) & 1u)) >> 16);
}
__device__ inline float bf2f(unsigned short h) { return __uint_as_float(((unsigned)h) << 16); }

// ================= prep_all: block-specialized =================
// b in [0,256)   : Pcat[d, h*128+k] = sum_c Wo[d,h*128+c] * W[h*128+c, k]
//                  written in MFMA B-fragment-packed order (split bf16)
// b in [256,384) : cvec[d] = sum_j bias[j]*Wo[d,j] + bo[d]
// b in [384,386) : w_src[h,d] = sum_c att_src[h,c]*W[h*128+c, d]  (and w_dst)
// b in [386,394) : zero cursor[0..2047]
__global__ __launch_bounds__(256) void prep_all(const float* __restrict__ W,
                                                const float* __restrict__ att_src,
                                                const float* __restrict__ att_dst,
                                                const float* __restrict__ bias,
                                                const float* __restrict__ Wo,
                                                const float* __restrict__ bo,
                                                float* __restrict__ w_src,
                                                float* __restrict__ w_dst,
                                                unsigned short* __restrict__ p_hi,
                                                unsigned short* __restrict__ p_lo,
                                                float* __restrict__ cvec,
                                                int* __restrict__ cursor) {
    __shared__ float part[4];
    const int b = blockIdx.x, tid = threadIdx.x;
    if (b < 256) {                      // --- prep_P (fragment-packed) ---
        int h = b & 3;
        int d = (b >> 2) * 2 + (tid >> 7);
        int k = tid & 127;
        float acc = 0.f;
        for (int c = 0; c < D; ++c)
            acc += Wo[d * HC + h * D + c] * W[(h * D + c) * D + k];
        unsigned short hi = f2bf(acc);
        // B-fragment packing for mfma_f32_16x16x32_bf16:
        // element (col=d, kglobal=h*128+k) lives at lane=(kin>>3)*16+(d&15), j=kin&7
        int ct = d >> 4, lrow = d & 15;
        int kg = h * D + k, kstep = kg >> 5, kin = kg & 31;
        size_t idx = ((size_t)(ct * 16 + kstep) * 64 + (kin >> 3) * 16 + lrow) * 8 + (kin & 7);
        p_hi[idx] = hi;
        p_lo[idx] = f2bf(acc - bf2f(hi));
    } else if (b < 384) {               // --- prep_c ---
        int d = b - 256;
        float a = bias[tid] * Wo[d * HC + tid] + bias[tid + 256] * Wo[d * HC + tid + 256];
        #pragma unroll
        for (int off = 32; off; off >>= 1) a += __shfl_xor(a, off);
        if ((tid & 63) == 0) part[tid >> 6] = a;
        __syncthreads();
        if (tid == 0) cvec[d] = part[0] + part[1] + part[2] + part[3] + bo[d];
    } else if (b < 386) {               // --- prep_w ---
        int t = (b - 384) * 256 + tid;  // 0..511
        int h = t >> 7, dd = t & 127;
        float ws = 0.f, wd = 0.f;
        for (int c = 0; c < D; ++c) {
            float wv = W[(h * D + c) * D + dd];
            ws += att_src[h * D + c] * wv;
            wd += att_dst[h * D + c] * wv;
        }
        w_src[t] = ws;
        w_dst[t] = wd;
    } else {                            // --- zero cursor ---
        int idx = (b - 386) * 256 + tid;
        if (idx < SEQ) cursor[idx] = 0;
    }
}

// ======== att_fill: a_src/a_dst per node; first 256 blocks also bucket the edges ========
__global__ __launch_bounds__(256) void att_fill(const float* __restrict__ s,
                                                const float* __restrict__ w_src,
                                                const float* __restrict__ w_dst,
                                                const int* __restrict__ ei,
                                                float* __restrict__ a_src,
                                                float* __restrict__ a_dst,
                                                int* __restrict__ cursor,
                                                int* __restrict__ csr0) {
    const int bid = blockIdx.x, tid = threadIdx.x;
    if (bid < 256) {                    // bucket-fill: one edge per thread
        int e = bid * 256 + tid;
        int src = ei[e], dst = ei[E + e];
        int slot = atomicAdd(&cursor[dst], 1);
        if (slot < SLOTS) csr0[dst * SLOTS + slot] = src;
    }
    const int wave = tid >> 6, lane = tid & 63;
    const int n = bid * 4 + wave;
    float s0 = s[n * D + lane];
    float s1 = s[n * D + 64 + lane];
    #pragma unroll
    for (int h = 0; h < H; ++h) {
        float ps = s0 * w_src[h * D + lane] + s1 * w_src[h * D + 64 + lane];
        float pd = s0 * w_dst[h * D + lane] + s1 * w_dst[h * D + 64 + lane];
        #pragma unroll
        for (int off = 32; off; off >>= 1) {
            ps += __shfl_xor(ps, off);
            pd += __shfl_xor(pd, off);
        }
        if (lane == 0) {
            a_src[n * H + h] = ps;
            a_dst[n * H + h] = pd;
        }
    }
}

// ======== per-dst softmax + gather of s rows -> z (split bf16) ========
__global__ __launch_bounds__(256) void node_aggregate_z(const int* __restrict__ cursor,
                                                        const int* __restrict__ csr0,
                                                        const float* __restrict__ a_src,
                                                        const float* __restrict__ a_dst,
                                                        const float* __restrict__ s,
                                                        unsigned short* __restrict__ z_hi,
                                                        unsigned short* __restrict__ z_lo) {
    __shared__ float sh_alpha[4][MAXE][4];
    __shared__ int   sh_src[4][MAXE];
    const int wave = threadIdx.x >> 6, lane = threadIdx.x & 63;
    const int n = blockIdx.x * 4 + wave;
    const int b = n >> 11, dloc = n & 2047;
    int deg = cursor[dloc];
    deg = (deg < SLOTS) ? deg : SLOTS;
    const int beg = dloc * SLOTS;
    const int cnt = deg + 1;                      // + self loop
    float4 adv = *reinterpret_cast<const float4*>(&a_dst[n * H]);
    float ad[4] = {adv.x, adv.y, adv.z, adv.w};
    float mx[4] = {-1e30f, -1e30f, -1e30f, -1e30f};
    for (int i = lane; i < cnt; i += 64) {
        int sg = (i < deg) ? (csr0[beg + i] + (b << 11)) : n;
        sh_src[wave][i] = sg;
        float4 asv = *reinterpret_cast<const float4*>(&a_src[sg * H]);
        float lg[4] = {asv.x, asv.y, asv.z, asv.w};
        #pragma unroll
        for (int h = 0; h < 4; ++h) {
            float l = lg[h] + ad[h];
            l = (l > 0.f) ? l : 0.2f * l;
            sh_alpha[wave][i][h] = l;
            mx[h] = fmaxf(mx[h], l);
        }
    }
    #pragma unroll
    for (int h = 0; h < 4; ++h)
        #pragma unroll
        for (int off = 32; off; off >>= 1) mx[h] = fmaxf(mx[h], __shfl_xor(mx[h], off));
    float sm[4] = {0.f, 0.f, 0.f, 0.f};
    for (int i = lane; i < cnt; i += 64) {
        #pragma unroll
        for (int h = 0; h < 4; ++h) {
            float ev = expf(sh_alpha[wave][i][h] - mx[h]);
            sh_alpha[wave][i][h] = ev;
            sm[h] += ev;
        }
    }
    #pragma unroll
    for (int h = 0; h < 4; ++h)
        #pragma unroll
        for (int off = 32; off; off >>= 1) sm[h] += __shfl_xor(sm[h], off);
    __syncthreads();
    float inv[4];
    #pragma unroll
    for (int h = 0; h < 4; ++h) inv[h] = 1.f / sm[h];

    // gather: lanes 0-31 take even edges, lanes 32-63 odd edges; float4 (4 cols) per lane
    const int half = lane >> 5, l32 = lane & 31;
    const int coff = l32 * 4;
    float acc[4][4] = {};                 // [head][col]
    for (int i = 0; i < cnt; i += 2) {
        int ii = i + half;
        if (ii < cnt) {
            int sg = sh_src[wave][ii];
            float4 sv = *reinterpret_cast<const float4*>(&s[(size_t)sg * D + coff]);
            float4 alv = *reinterpret_cast<const float4*>(&sh_alpha[wave][ii][0]);
            float al[4] = {alv.x, alv.y, alv.z, alv.w};
            float cv[4] = {sv.x, sv.y, sv.z, sv.w};
            #pragma unroll
            for (int h = 0; h < 4; ++h)
                #pragma unroll
                for (int c = 0; c < 4; ++c) acc[h][c] += al[h] * cv[c];
        }
    }
    #pragma unroll
    for (int h = 0; h < 4; ++h)
        #pragma unroll
        for (int c = 0; c < 4; ++c) acc[h][c] += __shfl_xor(acc[h][c], 32);
    // this lane writes heads {half*2, half*2+1}, cols coff..coff+3
    #pragma unroll
    for (int hh = 0; hh < 2; ++hh) {
        int h = half * 2 + hh;
        ushort4 zh, zl;
        float v0 = acc[h][0] * inv[h], v1 = acc[h][1] * inv[h];
        float v2 = acc[h][2] * inv[h], v3 = acc[h][3] * inv[h];
        zh.x = f2bf(v0); zh.y = f2bf(v1); zh.z = f2bf(v2); zh.w = f2bf(v3);
        zl.x = f2bf(v0 - bf2f(zh.x)); zl.y = f2bf(v1 - bf2f(zh.y));
        zl.z = f2bf(v2 - bf2f(zh.z)); zl.w = f2bf(v3 - bf2f(zh.w));
        *reinterpret_cast<ushort4*>(&z_hi[(size_t)n * HC + h * D + coff]) = zh;
        *reinterpret_cast<ushort4*>(&z_lo[(size_t)n * HC + h * D + coff]) = zl;
    }
}

// ======== out[m,d] = z[m,:] . Pcat[d,:] + cvec[d]  (split-bf16 MFMA) ========
// 512 blocks x 8 waves; block owns 16 rows, wave owns one 16-col tile (ct = wave).
__global__ __launch_bounds__(512) void out_mfma(const unsigned short* __restrict__ z_hi,
                                                const unsigned short* __restrict__ z_lo,
                                                const unsigned short* __restrict__ p_hi,
                                                const unsigned short* __restrict__ p_lo,
                                                const float* __restrict__ cvec,
                                                float* __restrict__ out) {
    const int ct = threadIdx.x >> 6, lane = threadIdx.x & 63;
    const int m0 = blockIdx.x * 16;
    const int lrow = lane & 15, lk8 = (lane >> 4) * 8;
    f32x4 acc = {0.f, 0.f, 0.f, 0.f};
    const unsigned short* za = z_hi + (size_t)(m0 + lrow) * HC + lk8;
    const unsigned short* zb = z_lo + (size_t)(m0 + lrow) * HC + lk8;
    const unsigned short* ph = p_hi + ((size_t)ct * 16 * 64 + lane) * 8;
    const unsigned short* pl = p_lo + ((size_t)ct * 16 * 64 + lane) * 8;
    #pragma unroll
    for (int ks = 0; ks < 16; ++ks) {
        s16x8 ah = *reinterpret_cast<const s16x8*>(za + ks * 32);
        s16x8 al = *reinterpret_cast<const s16x8*>(zb + ks * 32);
        s16x8 bh = *reinterpret_cast<const s16x8*>(ph + (size_t)ks * 512);
        s16x8 bl = *reinterpret_cast<const s16x8*>(pl + (size_t)ks * 512);
        acc = __builtin_amdgcn_mfma_f32_16x16x32_bf16(ah, bh, acc, 0, 0, 0);
        acc = __builtin_amdgcn_mfma_f32_16x16x32_bf16(ah, bl, acc, 0, 0, 0);
        acc = __builtin_amdgcn_mfma_f32_16x16x32_bf16(al, bh, acc, 0, 0, 0);
    }
    // C/D layout: col = lane&15, row = (lane>>4)*4 + reg
    const int orow = m0 + (lane >> 4) * 4;
    const int ocol = ct * 16 + (lane & 15);
    const float cb = cvec[ocol];
    #pragma unroll
    for (int r = 0; r < 4; ++r)
        out[(size_t)(orow + r) * D + ocol] = acc[r] + cb;
}

extern "C" void kernel_launch(void* const* d_in, const int* in_sizes, int n_in,
                              void* d_out, int out_size, void* d_ws, size_t ws_size,
                              hipStream_t stream) {
    const float* s       = (const float*)d_in[0];
    const int*   ei      = (const int*)d_in[1];
    const float* W       = (const float*)d_in[2];
    const float* att_src = (const float*)d_in[3];
    const float* att_dst = (const float*)d_in[4];
    const float* bias    = (const float*)d_in[5];
    const float* Wo      = (const float*)d_in[6];
    const float* bo      = (const float*)d_in[7];
    float* out = (float*)d_out;

    char* ws = (char*)d_ws;
    float* w_src = (float*)ws; ws += 512 * 4;
    float* w_dst = (float*)ws; ws += 512 * 4;
    float* a_src = (float*)ws; ws += (size_t)N * H * 4;
    float* a_dst = (float*)ws; ws += (size_t)N * H * 4;
    float* cvec  = (float*)ws; ws += 512;
    unsigned short* z_hi = (unsigned short*)ws; ws += (size_t)N * HC * 2;
    unsigned short* z_lo = (unsigned short*)ws; ws += (size_t)N * HC * 2;
    unsigned short* p_hi = (unsigned short*)ws; ws += (size_t)D * HC * 2;
    unsigned short* p_lo = (unsigned short*)ws; ws += (size_t)D * HC * 2;
    int* cursor = (int*)ws; ws += SEQ * 4;
    int* csr0   = (int*)ws; ws += (size_t)SEQ * SLOTS * 4;

    prep_all<<<394, 256, 0, stream>>>(W, att_src, att_dst, bias, Wo, bo,
                                      w_src, w_dst, p_hi, p_lo, cvec, cursor);
    att_fill<<<N / 4, 256, 0, stream>>>(s, w_src, w_dst, ei, a_src, a_dst, cursor, csr0);
    node_aggregate_z<<<N / 4, 256, 0, stream>>>(cursor, csr0, a_src, a_dst, s, z_hi, z_lo);
    out_mfma<<<N / 16, 512, 0, stream>>>(z_hi, z_lo, p_hi, p_lo, cvec, out);
}

// Round 5
// 60.694 us; speedup vs baseline: 2.7681x; 1.1555x over previous
//
#include <hip/hip_runtime.h>

// Problem constants (fixed by reference)
constexpr int BSZ = 4, SEQ = 2048, D = 128, H = 4, E = 65536;
constexpr int N  = BSZ * SEQ;   // 8192 nodes
constexpr int HC = H * D;       // 512
constexpr int SLOTS = 128;      // per-dst bucket capacity; in-deg ~ Binom(65536,1/2048), mean 32
constexpr int MAXE  = SLOTS + 4;

typedef __attribute__((ext_vector_type(8))) short s16x8;
typedef __attribute__((ext_vector_type(4))) float f32x4;

__device__ inline unsigned short f2bf(float v) {            // fp32 -> bf16 RNE
    unsigned u = __float_as_uint(v);
    return (unsigned short)((u + 0x7fffu + ((u >> 16) & 1u)) >> 16);
}
__device__ inline float bf2f(unsigned short h) { return __uint_as_float(((unsigned)h) << 16); }

// ================= prep_all: block-specialized =================
// b in [0,256)   : Pcat[d, h*128+k] = sum_c Wo[d,h*128+c] * W[h*128+c, k]
//                  written in MFMA B-fragment-packed order (split bf16)
// b in [256,384) : cvec[d] = sum_j bias[j]*Wo[d,j] + bo[d]
// b in [384,386) : w_src[h,d] = sum_c att_src[h,c]*W[h*128+c, d]  (and w_dst)
// b in [386,394) : zero cursor[0..2047]
__global__ __launch_bounds__(256) void prep_all(const float* __restrict__ W,
                                                const float* __restrict__ att_src,
                                                const float* __restrict__ att_dst,
                                                const float* __restrict__ bias,
                                                const float* __restrict__ Wo,
                                                const float* __restrict__ bo,
                                                float* __restrict__ w_src,
                                                float* __restrict__ w_dst,
                                                unsigned short* __restrict__ p_hi,
                                                unsigned short* __restrict__ p_lo,
                                                float* __restrict__ cvec,
                                                int* __restrict__ cursor) {
    __shared__ float part[4];
    const int b = blockIdx.x, tid = threadIdx.x;
    if (b < 256) {                      // --- prep_P (fragment-packed) ---
        int h = b & 3;
        int d = (b >> 2) * 2 + (tid >> 7);
        int k = tid & 127;
        float acc = 0.f;
        for (int c = 0; c < D; ++c)
            acc += Wo[d * HC + h * D + c] * W[(h * D + c) * D + k];
        unsigned short hi = f2bf(acc);
        // B-fragment packing for mfma_f32_16x16x32_bf16:
        // element (col=d, kglobal=h*128+k) lives at lane=(kin>>3)*16+(d&15), j=kin&7
        int ct = d >> 4, lrow = d & 15;
        int kg = h * D + k, kstep = kg >> 5, kin = kg & 31;
        size_t idx = ((size_t)(ct * 16 + kstep) * 64 + (kin >> 3) * 16 + lrow) * 8 + (kin & 7);
        p_hi[idx] = hi;
        p_lo[idx] = f2bf(acc - bf2f(hi));
    } else if (b < 384) {               // --- prep_c ---
        int d = b - 256;
        float a = bias[tid] * Wo[d * HC + tid] + bias[tid + 256] * Wo[d * HC + tid + 256];
        #pragma unroll
        for (int off = 32; off; off >>= 1) a += __shfl_xor(a, off);
        if ((tid & 63) == 0) part[tid >> 6] = a;
        __syncthreads();
        if (tid == 0) cvec[d] = part[0] + part[1] + part[2] + part[3] + bo[d];
    } else if (b < 386) {               // --- prep_w ---
        int t = (b - 384) * 256 + tid;  // 0..511
        int h = t >> 7, dd = t & 127;
        float ws = 0.f, wd = 0.f;
        for (int c = 0; c < D; ++c) {
            float wv = W[(h * D + c) * D + dd];
            ws += att_src[h * D + c] * wv;
            wd += att_dst[h * D + c] * wv;
        }
        w_src[t] = ws;
        w_dst[t] = wd;
    } else {                            // --- zero cursor ---
        int idx = (b - 386) * 256 + tid;
        if (idx < SEQ) cursor[idx] = 0;
    }
}

// ======== att_fill: a_src/a_dst per node; first 256 blocks also bucket the edges ========
__global__ __launch_bounds__(256) void att_fill(const float* __restrict__ s,
                                                const float* __restrict__ w_src,
                                                const float* __restrict__ w_dst,
                                                const int* __restrict__ ei,
                                                float* __restrict__ a_src,
                                                float* __restrict__ a_dst,
                                                int* __restrict__ cursor,
                                                int* __restrict__ csr0) {
    const int bid = blockIdx.x, tid = threadIdx.x;
    if (bid < 256) {                    // bucket-fill: one edge per thread
        int e = bid * 256 + tid;
        int src = ei[e], dst = ei[E + e];
        int slot = atomicAdd(&cursor[dst], 1);
        if (slot < SLOTS) csr0[dst * SLOTS + slot] = src;
    }
    const int wave = tid >> 6, lane = tid & 63;
    const int n = bid * 4 + wave;
    float s0 = s[n * D + lane];
    float s1 = s[n * D + 64 + lane];
    #pragma unroll
    for (int h = 0; h < H; ++h) {
        float ps = s0 * w_src[h * D + lane] + s1 * w_src[h * D + 64 + lane];
        float pd = s0 * w_dst[h * D + lane] + s1 * w_dst[h * D + 64 + lane];
        #pragma unroll
        for (int off = 32; off; off >>= 1) {
            ps += __shfl_xor(ps, off);
            pd += __shfl_xor(pd, off);
        }
        if (lane == 0) {
            a_src[n * H + h] = ps;
            a_dst[n * H + h] = pd;
        }
    }
}

// ======== per-dst softmax + gather of s rows -> z (split bf16) ========
__global__ __launch_bounds__(256) void node_aggregate_z(const int* __restrict__ cursor,
                                                        const int* __restrict__ csr0,
                                                        const float* __restrict__ a_src,
                                                        const float* __restrict__ a_dst,
                                                        const float* __restrict__ s,
                                                        unsigned short* __restrict__ z_hi,
                                                        unsigned short* __restrict__ z_lo) {
    __shared__ float sh_alpha[4][MAXE][4];
    __shared__ int   sh_src[4][MAXE];
    const int wave = threadIdx.x >> 6, lane = threadIdx.x & 63;
    const int n = blockIdx.x * 4 + wave;
    const int b = n >> 11, dloc = n & 2047;
    int deg = cursor[dloc];
    deg = (deg < SLOTS) ? deg : SLOTS;
    const int beg = dloc * SLOTS;
    const int cnt = deg + 1;                      // + self loop
    float4 adv = *reinterpret_cast<const float4*>(&a_dst[n * H]);
    float ad[4] = {adv.x, adv.y, adv.z, adv.w};
    float mx[4] = {-1e30f, -1e30f, -1e30f, -1e30f};
    for (int i = lane; i < cnt; i += 64) {
        int sg = (i < deg) ? (csr0[beg + i] + (b << 11)) : n;
        sh_src[wave][i] = sg;
        float4 asv = *reinterpret_cast<const float4*>(&a_src[sg * H]);
        float lg[4] = {asv.x, asv.y, asv.z, asv.w};
        #pragma unroll
        for (int h = 0; h < 4; ++h) {
            float l = lg[h] + ad[h];
            l = (l > 0.f) ? l : 0.2f * l;
            sh_alpha[wave][i][h] = l;
            mx[h] = fmaxf(mx[h], l);
        }
    }
    #pragma unroll
    for (int h = 0; h < 4; ++h)
        #pragma unroll
        for (int off = 32; off; off >>= 1) mx[h] = fmaxf(mx[h], __shfl_xor(mx[h], off));
    float sm[4] = {0.f, 0.f, 0.f, 0.f};
    for (int i = lane; i < cnt; i += 64) {
        #pragma unroll
        for (int h = 0; h < 4; ++h) {
            float ev = expf(sh_alpha[wave][i][h] - mx[h]);
            sh_alpha[wave][i][h] = ev;
            sm[h] += ev;
        }
    }
    #pragma unroll
    for (int h = 0; h < 4; ++h)
        #pragma unroll
        for (int off = 32; off; off >>= 1) sm[h] += __shfl_xor(sm[h], off);
    __syncthreads();
    float inv[4];
    #pragma unroll
    for (int h = 0; h < 4; ++h) inv[h] = 1.f / sm[h];

    // gather: lanes 0-31 take even edges, lanes 32-63 odd edges; float4 (4 cols) per lane
    const int half = lane >> 5, l32 = lane & 31;
    const int coff = l32 * 4;
    float acc[4][4] = {};                 // [head][col]
    for (int i = 0; i < cnt; i += 2) {
        int ii = i + half;
        if (ii < cnt) {
            int sg = sh_src[wave][ii];
            float4 sv = *reinterpret_cast<const float4*>(&s[(size_t)sg * D + coff]);
            float4 alv = *reinterpret_cast<const float4*>(&sh_alpha[wave][ii][0]);
            float al[4] = {alv.x, alv.y, alv.z, alv.w};
            float cv[4] = {sv.x, sv.y, sv.z, sv.w};
            #pragma unroll
            for (int h = 0; h < 4; ++h)
                #pragma unroll
                for (int c = 0; c < 4; ++c) acc[h][c] += al[h] * cv[c];
        }
    }
    #pragma unroll
    for (int h = 0; h < 4; ++h)
        #pragma unroll
        for (int c = 0; c < 4; ++c) acc[h][c] += __shfl_xor(acc[h][c], 32);
    // this lane writes heads {half*2, half*2+1}, cols coff..coff+3
    #pragma unroll
    for (int hh = 0; hh < 2; ++hh) {
        int h = half * 2 + hh;
        ushort4 zh, zl;
        float v0 = acc[h][0] * inv[h], v1 = acc[h][1] * inv[h];
        float v2 = acc[h][2] * inv[h], v3 = acc[h][3] * inv[h];
        zh.x = f2bf(v0); zh.y = f2bf(v1); zh.z = f2bf(v2); zh.w = f2bf(v3);
        zl.x = f2bf(v0 - bf2f(zh.x)); zl.y = f2bf(v1 - bf2f(zh.y));
        zl.z = f2bf(v2 - bf2f(zh.z)); zl.w = f2bf(v3 - bf2f(zh.w));
        *reinterpret_cast<ushort4*>(&z_hi[(size_t)n * HC + h * D + coff]) = zh;
        *reinterpret_cast<ushort4*>(&z_lo[(size_t)n * HC + h * D + coff]) = zl;
    }
}

// ======== out[m,d] = z[m,:] . Pcat[d,:] + cvec[d]  (split-bf16 MFMA, LDS-staged z) ====
// Grid: 128 row-tiles x 2 col-halves = 256 blocks, 512 threads (8 waves).
// Block tile: 64 rows x 64 cols. z (hi+lo) staged once in LDS (130 KB).
// Wave w: col-tile ct = w&3 (16 cols within the half), mgrp pair = (w>>2)*2 + {0,1}.
constexpr int ZPAD = 520;   // 512 + 8 shorts: breaks the 1024B row-stride bank alias
__global__ __launch_bounds__(512) void out_mfma(const unsigned short* __restrict__ z_hi,
                                                const unsigned short* __restrict__ z_lo,
                                                const unsigned short* __restrict__ p_hi,
                                                const unsigned short* __restrict__ p_lo,
                                                const float* __restrict__ cvec,
                                                float* __restrict__ out) {
    __shared__ short zlds[2][64][ZPAD];
    const int tid = threadIdx.x;
    const int m0 = (blockIdx.x >> 1) * 64;          // 64-row tile
    const int chalf = blockIdx.x & 1;               // which 64-col half
    // ---- stage z hi+lo into LDS (coalesced 16B/lane reads, linear 16B writes) ----
    {
        const int rl = tid >> 6;                    // 0..7
        const int kc = tid & 63;                    // 16B chunk within row
        #pragma unroll
        for (int p = 0; p < 8; ++p) {
            int r = p * 8 + rl;
            s16x8 vh = *reinterpret_cast<const s16x8*>(z_hi + (size_t)(m0 + r) * HC + kc * 8);
            s16x8 vl = *reinterpret_cast<const s16x8*>(z_lo + (size_t)(m0 + r) * HC + kc * 8);
            *reinterpret_cast<s16x8*>(&zlds[0][r][kc * 8]) = vh;
            *reinterpret_cast<s16x8*>(&zlds[1][r][kc * 8]) = vl;
        }
    }
    __syncthreads();
    // ---- compute ----
    const int w = tid >> 6, lane = tid & 63;
    const int ct = chalf * 4 + (w & 3);             // global 16-col tile 0..7
    const int mg0 = (w >> 2) * 2;                   // first mgrp of this wave
    const int lrow = lane & 15, lkoff = (lane >> 4) * 8;
    f32x4 acc0 = {0.f, 0.f, 0.f, 0.f}, acc1 = {0.f, 0.f, 0.f, 0.f};
    const unsigned short* pb = p_hi + ((size_t)ct * 16 * 64 + lane) * 8;
    const unsigned short* pbl = p_lo + ((size_t)ct * 16 * 64 + lane) * 8;
    const short* a0 = &zlds[0][mg0 * 16 + lrow][lkoff];
    const short* a0l = &zlds[1][mg0 * 16 + lrow][lkoff];
    const short* a1 = &zlds[0][mg0 * 16 + 16 + lrow][lkoff];
    const short* a1l = &zlds[1][mg0 * 16 + 16 + lrow][lkoff];
    #pragma unroll
    for (int ks = 0; ks < 16; ++ks) {
        s16x8 bh = *reinterpret_cast<const s16x8*>(pb + (size_t)ks * 512);
        s16x8 bl = *reinterpret_cast<const s16x8*>(pbl + (size_t)ks * 512);
        s16x8 ah0 = *reinterpret_cast<const s16x8*>(a0 + ks * 32);
        s16x8 al0 = *reinterpret_cast<const s16x8*>(a0l + ks * 32);
        s16x8 ah1 = *reinterpret_cast<const s16x8*>(a1 + ks * 32);
        s16x8 al1 = *reinterpret_cast<const s16x8*>(a1l + ks * 32);
        acc0 = __builtin_amdgcn_mfma_f32_16x16x32_bf16(ah0, bh, acc0, 0, 0, 0);
        acc0 = __builtin_amdgcn_mfma_f32_16x16x32_bf16(ah0, bl, acc0, 0, 0, 0);
        acc0 = __builtin_amdgcn_mfma_f32_16x16x32_bf16(al0, bh, acc0, 0, 0, 0);
        acc1 = __builtin_amdgcn_mfma_f32_16x16x32_bf16(ah1, bh, acc1, 0, 0, 0);
        acc1 = __builtin_amdgcn_mfma_f32_16x16x32_bf16(ah1, bl, acc1, 0, 0, 0);
        acc1 = __builtin_amdgcn_mfma_f32_16x16x32_bf16(al1, bh, acc1, 0, 0, 0);
    }
    // C/D layout: col = lane&15, row = (lane>>4)*4 + reg
    const int ocol = ct * 16 + (lane & 15);
    const int orow0 = m0 + mg0 * 16 + (lane >> 4) * 4;
    const float cb = cvec[ocol];
    #pragma unroll
    for (int r = 0; r < 4; ++r) {
        out[(size_t)(orow0 + r) * D + ocol]      = acc0[r] + cb;
        out[(size_t)(orow0 + 16 + r) * D + ocol] = acc1[r] + cb;
    }
}

extern "C" void kernel_launch(void* const* d_in, const int* in_sizes, int n_in,
                              void* d_out, int out_size, void* d_ws, size_t ws_size,
                              hipStream_t stream) {
    const float* s       = (const float*)d_in[0];
    const int*   ei      = (const int*)d_in[1];
    const float* W       = (const float*)d_in[2];
    const float* att_src = (const float*)d_in[3];
    const float* att_dst = (const float*)d_in[4];
    const float* bias    = (const float*)d_in[5];
    const float* Wo      = (const float*)d_in[6];
    const float* bo      = (const float*)d_in[7];
    float* out = (float*)d_out;

    char* ws = (char*)d_ws;
    float* w_src = (float*)ws; ws += 512 * 4;
    float* w_dst = (float*)ws; ws += 512 * 4;
    float* a_src = (float*)ws; ws += (size_t)N * H * 4;
    float* a_dst = (float*)ws; ws += (size_t)N * H * 4;
    float* cvec  = (float*)ws; ws += 512;
    unsigned short* z_hi = (unsigned short*)ws; ws += (size_t)N * HC * 2;
    unsigned short* z_lo = (unsigned short*)ws; ws += (size_t)N * HC * 2;
    unsigned short* p_hi = (unsigned short*)ws; ws += (size_t)D * HC * 2;
    unsigned short* p_lo = (unsigned short*)ws; ws += (size_t)D * HC * 2;
    int* cursor = (int*)ws; ws += SEQ * 4;
    int* csr0   = (int*)ws; ws += (size_t)SEQ * SLOTS * 4;

    prep_all<<<394, 256, 0, stream>>>(W, att_src, att_dst, bias, Wo, bo,
                                      w_src, w_dst, p_hi, p_lo, cvec, cursor);
    att_fill<<<N / 4, 256, 0, stream>>>(s, w_src, w_dst, ei, a_src, a_dst, cursor, csr0);
    node_aggregate_z<<<N / 4, 256, 0, stream>>>(cursor, csr0, a_src, a_dst, s, z_hi, z_lo);
    out_mfma<<<N / 32, 512, 0, stream>>>(z_hi, z_lo, p_hi, p_lo, cvec, out);
}